// Round 11
// baseline (13.079 us; speedup 1.0000x reference)
//
#include <hip/hip_runtime.h>

// Exponential concordance loss — 4-chunks-per-block, two-kernel structure:
// loss_sum = sum over (a,b) with dur[b] < dur[a] and ev[b]==1 of exp(p[a]-p[b])
//          = sum_b w[b] * S_b,  w[b]=ev[b]?exp(-p[b]):0,
//   S_b = sum of exp(p[a]) over rows a with dur_a > dur_b.
// Block = (256 columns) x (4 chunks of 64 rows). Wave w bitonic-sorts chunk w
// in registers (shuffles), suffix-scans exp(p), publishes sdur/ssuf to LDS.
// Each thread owns ONE column: 1 load + 1 exp amortized over 4 chunk searches
// (6-step branchless binary search + suffix lookup each). Wave shuffle-reduce,
// 4-way cross-wave combine -> block partial. Tiny finalize kernel reduces 1024
// partials in fixed order (in-kernel grid sync proved slower, R4-R7/R9).

#define TPB 256
#define ACHUNK 64     // rows per chunk == one wave
#define WPB 4         // chunks per block (one per wave)

__global__ void __launch_bounds__(TPB) pair_fused(const float* __restrict__ preds,
                                                  const float2* __restrict__ targets, // (dur, ev)
                                                  float* __restrict__ psum,
                                                  int* __restrict__ pcnt,
                                                  int n) {
    const int colGroups = n / TPB;                 // 8192/256 = 32
    const int cg  = blockIdx.x % colGroups;
    const int acg = blockIdx.x / colGroups;        // 0..31 chunk-group
    const int wid  = threadIdx.x >> 6;             // 0..3
    const int lane = threadIdx.x & 63;
    const int base_a = (acg * WPB + wid) * ACHUNK;
    const int b      = cg * TPB + threadIdx.x;     // this thread's column

    __shared__ float sdur[WPB][ACHUNK];            // sorted durations (ascending)
    __shared__ float ssuf[WPB][ACHUNK + 1];        // suffix sums of epos; [64]=0

    // ---- every wave: load its chunk, bitonic sort by dur, suffix-scan epos ----
    {
        float2 t  = targets[base_a + lane];
        float dur = t.x;
        float ep  = __expf(preds[base_a + lane]);
#pragma unroll
        for (int k = 2; k <= 64; k <<= 1) {
#pragma unroll
            for (int j = k >> 1; j > 0; j >>= 1) {
                float od = __shfl_xor(dur, j, 64);
                float oe = __shfl_xor(ep,  j, 64);
                bool lower    = (lane & j) == 0;
                bool asc      = (lane & k) == 0;   // k=64: all ascending
                bool take_min = (lower == asc);
                bool take_other = take_min ? (od < dur) : (od > dur);
                dur = take_other ? od : dur;
                ep  = take_other ? oe : ep;
            }
        }
        float suf = ep;                            // inclusive suffix sum
#pragma unroll
        for (int d = 1; d < 64; d <<= 1) {
            float v = __shfl_down(suf, d, 64);
            suf += (lane + d < 64) ? v : 0.0f;
        }
        sdur[wid][lane] = dur;
        ssuf[wid][lane] = suf;
        if (lane == 0) ssuf[wid][ACHUNK] = 0.0f;
    }

    // ---- each thread: one column load + one exp (overlaps sort epilogue) ----
    float2 tb = targets[b];
    float  qb = tb.x;
    float  wb = (tb.y == 1.0f) ? __expf(-preds[b]) : 0.0f;
    __syncthreads();

    // ---- search all 4 chunks for this column ----
    float csum = 0.0f;
    int   ccnt = 0;
#pragma unroll
    for (int c = 0; c < WPB; ++c) {
        int pos = 0;                               // count of dur_a <= q
#pragma unroll
        for (int s = 32; s > 0; s >>= 1)
            pos += (sdur[c][pos + s - 1] <= qb) ? s : 0;
        csum += ssuf[c][pos];
        ccnt += (ACHUNK - pos);
    }
    float lsum = (wb > 0.0f) ? wb * csum : 0.0f;   // ev[b]==1 <=> w_b>0
    int   lcnt = (wb > 0.0f) ? ccnt : 0;

    // ---- wave shuffle-reduce (no barriers), then 4-way combine ----
#pragma unroll
    for (int d = 32; d > 0; d >>= 1) {
        lsum += __shfl_down(lsum, d, 64);
        lcnt += __shfl_down(lcnt, d, 64);
    }
    __shared__ float wsum[WPB];
    __shared__ int   wcnt[WPB];
    if (lane == 0) { wsum[wid] = lsum; wcnt[wid] = lcnt; }
    __syncthreads();
    if (threadIdx.x == 0) {
        psum[blockIdx.x] = (wsum[0] + wsum[1]) + (wsum[2] + wsum[3]);
        pcnt[blockIdx.x] = wcnt[0] + wcnt[1] + wcnt[2] + wcnt[3];
    }
}

__global__ void __launch_bounds__(TPB) finalize_kernel(const float* __restrict__ psum,
                                                       const int* __restrict__ pcnt,
                                                       float* __restrict__ out,
                                                       int nb) {
    __shared__ double    ds[TPB];
    __shared__ long long dc[TPB];
    double    ls = 0.0;
    long long lc = 0;
    for (int i = threadIdx.x; i < nb; i += TPB) {
        ls += (double)psum[i];
        lc += (long long)pcnt[i];
    }
    ds[threadIdx.x] = ls;
    dc[threadIdx.x] = lc;
    __syncthreads();
    for (int s = TPB / 2; s > 0; s >>= 1) {
        if (threadIdx.x < s) {
            ds[threadIdx.x] += ds[threadIdx.x + s];
            dc[threadIdx.x] += dc[threadIdx.x + s];
        }
        __syncthreads();
    }
    if (threadIdx.x == 0) {
        out[0] = (dc[0] > 0) ? (float)(ds[0] / (double)dc[0]) : 0.0f;
    }
}

extern "C" void kernel_launch(void* const* d_in, const int* in_sizes, int n_in,
                              void* d_out, int out_size, void* d_ws, size_t ws_size,
                              hipStream_t stream) {
    const float*  preds   = (const float*)d_in[0];
    const float2* targets = (const float2*)d_in[1];   // [n] of (dur, ev)
    float* out = (float*)d_out;
    int n = in_sizes[0];   // 8192

    int colGroups   = n / TPB;                     // 32
    int chunkGroups = n / (ACHUNK * WPB);          // 32
    int nblocks     = colGroups * chunkGroups;     // 1024

    // ws layout: psum[nblocks] f32, pcnt[nblocks] i32
    float* psum = (float*)d_ws;
    int*   pcnt = (int*)(psum + nblocks);

    pair_fused<<<nblocks, TPB, 0, stream>>>(preds, targets, psum, pcnt, n);
    finalize_kernel<<<1, TPB, 0, stream>>>(psum, pcnt, out, nblocks);
}